// Round 8
// baseline (312.758 us; speedup 1.0000x reference)
//
#include <hip/hip_runtime.h>

#define N_NODES 100000
#define N_FEAT  256
#define N_HID   64
#define N_EDGES 1600000
#define NEG_SLOPE 0.05f

#define NBUCKET 391   // ceil(N_NODES / 256); bucket b = nodes [b*256, b*256+256)
#define TILE    1024  // edges per tile (small tile -> 1563 blocks -> 6 blk/CU)
#define NTILES  ((N_EDGES + TILE - 1) / TILE)  // 1563
#define EPT     (TILE / 256)                   // edges per thread in a tile
#define BCAP    4704  // per-bucket record capacity (mean 4092, +9.5 sigma)
#define BTHREADS 1024 // k_bucket block size (16 waves; 2 blocks/CU co-resident)

typedef float  floatx4 __attribute__((ext_vector_type(4)));
typedef short  shortx8 __attribute__((ext_vector_type(8)));

__device__ __forceinline__ unsigned short f2bf(float f) {
  unsigned int u = __float_as_uint(f);
  u = u + 0x7fffu + ((u >> 16) & 1u);  // RNE
  return (unsigned short)(u >> 16);
}
__device__ __forceinline__ float bf_lo(unsigned int u) {
  return __uint_as_float(u << 16);
}
__device__ __forceinline__ float bf_hi(unsigned int u) {
  return __uint_as_float(u & 0xFFFF0000u);
}

// wave64 inclusive scan (no barriers)
__device__ __forceinline__ int wave_iscan(int v, int lane) {
#pragma unroll
  for (int d = 1; d < 64; d <<= 1) {
    int tv = __shfl_up(v, d);
    if (lane >= d) v += tv;
  }
  return v;
}

// ---------------------------------------------------------------------------
// K0: W prep — WbT[n][k] = bf16(W[k][n]); also zero the 391 bucket cursors.
// ---------------------------------------------------------------------------
__global__ __launch_bounds__(256) void k_wprep(const float* __restrict__ W,
                                               unsigned short* __restrict__ WbT,
                                               int* __restrict__ cursor) {
  int n = blockIdx.x;
  int k = threadIdx.x;
  WbT[n * 256 + k] = f2bf(W[(size_t)k * N_HID + n]);
  int i = blockIdx.x * 256 + threadIdx.x;
  if (i < NBUCKET) cursor[i] = 0;
}

// ---------------------------------------------------------------------------
// K2: per-tile bucket histogram ONLY (LDS atomics, no global atomics).
//     Standalone so its atomic latency never sits on k_bin's critical path.
// ---------------------------------------------------------------------------
__global__ __launch_bounds__(256) void k_histT(const int* __restrict__ ei,
                                               int* __restrict__ tileCnt) {
  __shared__ int hist[NBUCKET];
  const int t = threadIdx.x;
  const int e0 = blockIdx.x * TILE;
  const int ecnt = min(TILE, N_EDGES - e0);

  for (int i = t; i < NBUCKET; i += 256) hist[i] = 0;
  __syncthreads();

#pragma unroll
  for (int j = 0; j < EPT; ++j) {
    int li = j * 256 + t;
    if (li < ecnt) atomicAdd(&hist[ei[e0 + li] >> 8], 1);
  }
  __syncthreads();

  for (int b = t; b < NBUCKET; b += 256)
    tileCnt[blockIdx.x * NBUCKET + b] = hist[b];
}

// ---------------------------------------------------------------------------
// K1: MFMA bf16 GEMM (wave = 16 rows x 64 cols; A streamed from global),
//     fused s1/s2; Wh stored bf16.
// ---------------------------------------------------------------------------
#define WSTRIDE 264
__global__ __launch_bounds__(256) void k_gemm(
    const float* __restrict__ x, const unsigned short* __restrict__ WbT,
    const float* __restrict__ aw, unsigned short* __restrict__ Whb,
    float* __restrict__ s1, float* __restrict__ s2) {
  __shared__ unsigned short wsm[64 * WSTRIDE];

  const int t = threadIdx.x;
  for (int idx = t; idx < 64 * 32; idx += 256) {
    int row = idx >> 5, c16 = idx & 31;
    *(uint4*)(wsm + row * WSTRIDE + c16 * 8) =
        *(const uint4*)(WbT + row * 256 + c16 * 8);
  }
  __syncthreads();

  const int w = t >> 6;
  const int lane = t & 63;
  const int q = lane >> 4;
  const int li = lane & 15;
  const int r0 = blockIdx.x * 64;
  const int grow = r0 + w * 16 + li;
  const bool vrow = grow < N_NODES;

  float4 araw[16];
  if (vrow) {
    const float4* xr = (const float4*)(x + (size_t)grow * N_FEAT);
#pragma unroll
    for (int c = 0; c < 8; ++c) {
      araw[2 * c]     = xr[c * 8 + q * 2];
      araw[2 * c + 1] = xr[c * 8 + q * 2 + 1];
    }
  } else {
#pragma unroll
    for (int i = 0; i < 16; ++i) araw[i] = make_float4(0.f, 0.f, 0.f, 0.f);
  }

  floatx4 acc[4];
#pragma unroll
  for (int g = 0; g < 4; ++g) acc[g] = (floatx4){0.f, 0.f, 0.f, 0.f};

#pragma unroll
  for (int c = 0; c < 8; ++c) {
    float4 v0 = araw[2 * c], v1 = araw[2 * c + 1];
    shortx8 a;
    a[0] = (short)f2bf(v0.x); a[1] = (short)f2bf(v0.y);
    a[2] = (short)f2bf(v0.z); a[3] = (short)f2bf(v0.w);
    a[4] = (short)f2bf(v1.x); a[5] = (short)f2bf(v1.y);
    a[6] = (short)f2bf(v1.z); a[7] = (short)f2bf(v1.w);
#pragma unroll
    for (int g = 0; g < 4; ++g) {
      shortx8 b = *(const shortx8*)(wsm + (g * 16 + li) * WSTRIDE + c * 32 + q * 8);
      acc[g] = __builtin_amdgcn_mfma_f32_16x16x32_bf16(a, b, acc[g], 0, 0, 0);
    }
  }

#pragma unroll
  for (int j = 0; j < 4; ++j) {
    int r = r0 + w * 16 + q * 4 + j;
    if (r < N_NODES) {
#pragma unroll
      for (int g = 0; g < 4; ++g)
        Whb[(size_t)r * N_HID + g * 16 + li] = f2bf(acc[g][j]);
    }
  }

#pragma unroll
  for (int j = 0; j < 4; ++j) {
    float p1 = 0.f, p2 = 0.f;
#pragma unroll
    for (int g = 0; g < 4; ++g) {
      p1 += acc[g][j] * aw[g * 16 + li];
      p2 += acc[g][j] * aw[64 + g * 16 + li];
    }
#pragma unroll
    for (int off = 1; off < 16; off <<= 1) {
      p1 += __shfl_xor(p1, off);
      p2 += __shfl_xor(p2, off);
    }
    int r = r0 + w * 16 + q * 4 + j;
    if (li == 0 && r < N_NODES) {
      s1[r] = p1;
      s2[r] = p2;
    }
  }
}

// ---------------------------------------------------------------------------
// K4: binning with FIXED-CAPACITY bucket regions + cursor reservation.
//     Counts come from tileCnt (coalesced load, no in-kernel histogram).
//     One global atomicAdd per nonzero bucket reserves [res, res+hist[b]).
//     Within-bucket order nondeterministic (f32 sum-order noise only).
//     rec.x = dst | (src&255)<<17 ; rec.y = bits(h). h_orig[e] coalesced.
// ---------------------------------------------------------------------------
__global__ __launch_bounds__(256) void k_bin(
    const int* __restrict__ ei, const float* __restrict__ s1,
    const float* __restrict__ s2, const float* __restrict__ ab,
    const int* __restrict__ tileCnt, int* __restrict__ cursor,
    int2* __restrict__ binned, float* __restrict__ h_orig) {
  __shared__ int  scanx[NBUCKET];
  __shared__ int  fillc[NBUCKET];
  __shared__ int  gbase[NBUCKET];
  __shared__ int  wtot[4];
  __shared__ int2 sorted[TILE];
  __shared__ int  tgt[TILE];

  const int t = threadIdx.x;
  const int tile = blockIdx.x;
  const int e0 = tile * TILE;
  const int ecnt = min(TILE, N_EDGES - e0);
  const int lane = t & 63, wv = t >> 6;

  for (int b = t; b < NBUCKET; b += 256) fillc[b] = 0;

  // load per-tile counts (coalesced), scan (wave-shuffle), reserve ranges
  int b0 = t * 2, b1 = t * 2 + 1;
  int v0 = (b0 < NBUCKET) ? tileCnt[tile * NBUCKET + b0] : 0;
  int v1 = (b1 < NBUCKET) ? tileCnt[tile * NBUCKET + b1] : 0;
  int pairsum = v0 + v1;
  int p = wave_iscan(pairsum, lane);
  if (lane == 63) wtot[wv] = p;
  __syncthreads();
  int off = 0;
  for (int w2 = 0; w2 < wv; ++w2) off += wtot[w2];
  int base = off + p - pairsum;
  if (b0 < NBUCKET) {
    scanx[b0] = base;
    gbase[b0] = b0 * BCAP + (v0 ? atomicAdd(&cursor[b0], v0) : 0);
  }
  if (b1 < NBUCKET) {
    scanx[b1] = base + v0;
    gbase[b1] = b1 * BCAP + (v1 ? atomicAdd(&cursor[b1], v1) : 0);
  }
  __syncthreads();

  float bias = ab[0];
#pragma unroll
  for (int j = 0; j < EPT; ++j) {
    int li = j * 256 + t;
    if (li < ecnt) {
      int idx = e0 + li;
      int src = ei[idx];
      int dst = ei[N_EDGES + idx];
      float sc = s1[src] + s2[dst] + bias;
      float v = sc > 0.f ? sc : NEG_SLOPE * sc;
      float h = __expf(v);
      h_orig[idx] = h;
      int b = src >> 8;
      int slot = scanx[b] + atomicAdd(&fillc[b], 1);
      sorted[slot].x = dst | ((src & 255) << 17);
      sorted[slot].y = __float_as_int(h);
      int g = gbase[b] + (slot - scanx[b]);
      tgt[slot] = (g < (b + 1) * BCAP) ? g : -1;  // drop overflow (9.5 sigma)
    }
  }
  __syncthreads();

  for (int i = t; i < ecnt; i += 256) {
    int g = tgt[i];
    if (g >= 0) binned[g] = sorted[i];
  }
}

// ---------------------------------------------------------------------------
// K5: one block per bucket (256 nodes), 1024 threads (16 waves).
//     W0 = b*BCAP, cnt = min(cursor[b], BCAP). Two-pass local CSR build
//     (count -> shuffle-scan -> place), then 128 groups x 8 lanes aggregate
//     with deferred normalization. __launch_bounds__(1024,8) keeps VGPR<=64
//     so 2 blocks (32 waves) co-reside per CU.
// ---------------------------------------------------------------------------
__global__ __launch_bounds__(BTHREADS, 8) void k_bucket(
    const int* __restrict__ cursor, const int2* __restrict__ binned,
    const unsigned short* __restrict__ Whb, float* __restrict__ out,
    float* __restrict__ invh) {
  __shared__ int2  recs[BCAP];
  __shared__ int   startp[256];
  __shared__ int   curs[256];
  __shared__ int   wtot[4];

  const int t = threadIdx.x;
  const int lane = t & 63, wvx = t >> 6;
  const int b = blockIdx.x;
  const int node0 = b * 256;
  const int W0 = b * BCAP;
  const int cnt = min(cursor[b], BCAP);

  if (t < 256) curs[t] = 0;
  __syncthreads();

  // pass 1: per-node count (LDS atomics over the L2-hot binned window)
  for (int i = t; i < cnt; i += BTHREADS) {
    int rx = binned[W0 + i].x;
    atomicAdd(&curs[(rx >> 17) & 255], 1);
  }
  __syncthreads();

  // shuffle-scan of counts -> exclusive startp (first 256 threads)
  int v = 0;
  if (t < 256) v = curs[t];
  int p = wave_iscan(v, lane);
  if (t < 256 && lane == 63) wtot[wvx] = p;
  __syncthreads();
  if (t < 256) {
    int off = 0;
    for (int w2 = 0; w2 < wvx; ++w2) off += wtot[w2];
    int mystart = off + p - v;
    startp[t] = mystart;
    curs[t] = mystart;
  }
  __syncthreads();

  // pass 2: place records (no hsum atomics — normalization deferred)
  for (int i = t; i < cnt; i += BTHREADS) {
    int2 r = binned[W0 + i];
    int loc = (r.x >> 17) & 255;
    int slot = atomicAdd(&curs[loc], 1);
    if (slot < BCAP) {
      recs[slot].x = r.x & 0x1FFFF;
      recs[slot].y = r.y;
    }
  }
  __syncthreads();

  const int wv = t >> 6, lane2 = t & 63;
  const int grp = (wv << 3) | (lane2 >> 3);  // 0..127
  const int li = lane2 & 7;                  // dims li*8..li*8+7
  for (int j = grp; j < 256; j += 128) {
    int n2 = node0 + j;
    if (n2 >= N_NODES) break;
    int beg = startp[j];
    int endp = curs[j];
    if (endp > BCAP) endp = BCAP;  // safety, statistically never
    float hs = 0.f;
    float acc[8] = {};
    int r = beg;
    // 4x unrolled: 4 LDS rec reads -> 4 independent 16B gathers in flight
    for (; r + 4 <= endp; r += 4) {
      int2 e0 = recs[r];
      int2 e1 = recs[r + 1];
      int2 e2 = recs[r + 2];
      int2 e3 = recs[r + 3];
      uint4 w0 = *(const uint4*)(Whb + (size_t)e0.x * N_HID + li * 8);
      uint4 w1 = *(const uint4*)(Whb + (size_t)e1.x * N_HID + li * 8);
      uint4 w2 = *(const uint4*)(Whb + (size_t)e2.x * N_HID + li * 8);
      uint4 w3 = *(const uint4*)(Whb + (size_t)e3.x * N_HID + li * 8);
      float a0 = __int_as_float(e0.y);
      float a1 = __int_as_float(e1.y);
      float a2 = __int_as_float(e2.y);
      float a3 = __int_as_float(e3.y);
      hs += (a0 + a1) + (a2 + a3);
      acc[0] += a0 * bf_lo(w0.x); acc[1] += a0 * bf_hi(w0.x);
      acc[2] += a0 * bf_lo(w0.y); acc[3] += a0 * bf_hi(w0.y);
      acc[4] += a0 * bf_lo(w0.z); acc[5] += a0 * bf_hi(w0.z);
      acc[6] += a0 * bf_lo(w0.w); acc[7] += a0 * bf_hi(w0.w);
      acc[0] += a1 * bf_lo(w1.x); acc[1] += a1 * bf_hi(w1.x);
      acc[2] += a1 * bf_lo(w1.y); acc[3] += a1 * bf_hi(w1.y);
      acc[4] += a1 * bf_lo(w1.z); acc[5] += a1 * bf_hi(w1.z);
      acc[6] += a1 * bf_lo(w1.w); acc[7] += a1 * bf_hi(w1.w);
      acc[0] += a2 * bf_lo(w2.x); acc[1] += a2 * bf_hi(w2.x);
      acc[2] += a2 * bf_lo(w2.y); acc[3] += a2 * bf_hi(w2.y);
      acc[4] += a2 * bf_lo(w2.z); acc[5] += a2 * bf_hi(w2.z);
      acc[6] += a2 * bf_lo(w2.w); acc[7] += a2 * bf_hi(w2.w);
      acc[0] += a3 * bf_lo(w3.x); acc[1] += a3 * bf_hi(w3.x);
      acc[2] += a3 * bf_lo(w3.y); acc[3] += a3 * bf_hi(w3.y);
      acc[4] += a3 * bf_lo(w3.z); acc[5] += a3 * bf_hi(w3.z);
      acc[6] += a3 * bf_lo(w3.w); acc[7] += a3 * bf_hi(w3.w);
    }
    for (; r < endp; ++r) {
      int2 rec = recs[r];
      float a = __int_as_float(rec.y);
      hs += a;
      uint4 wvv = *(const uint4*)(Whb + (size_t)rec.x * N_HID + li * 8);
      acc[0] += a * bf_lo(wvv.x); acc[1] += a * bf_hi(wvv.x);
      acc[2] += a * bf_lo(wvv.y); acc[3] += a * bf_hi(wvv.y);
      acc[4] += a * bf_lo(wvv.z); acc[5] += a * bf_hi(wvv.z);
      acc[6] += a * bf_lo(wvv.w); acc[7] += a * bf_hi(wvv.w);
    }
    float inv = (endp > beg) ? 1.f / hs : 0.f;
    if (li == 0) invh[n2] = inv;
#pragma unroll
    for (int k = 0; k < 8; ++k) acc[k] *= inv;
    float* op = out + (size_t)n2 * N_HID + li * 8;
    *(float4*)op = make_float4(acc[0], acc[1], acc[2], acc[3]);
    *(float4*)(op + 4) = make_float4(acc[4], acc[5], acc[6], acc[7]);
  }
}

// ---------------------------------------------------------------------------
// K6: alpha[e] = h_orig[e] * invh[src]
// ---------------------------------------------------------------------------
__global__ __launch_bounds__(256) void k_alpha(
    const int* __restrict__ ei, const float* __restrict__ h_orig,
    const float* __restrict__ invh, float* __restrict__ alpha) {
  int e = blockIdx.x * 256 + threadIdx.x;
  if (e >= N_EDGES) return;
  alpha[e] = h_orig[e] * invh[ei[e]];
}

extern "C" void kernel_launch(void* const* d_in, const int* in_sizes, int n_in,
                              void* d_out, int out_size, void* d_ws,
                              size_t ws_size, hipStream_t stream) {
  const float* x  = (const float*)d_in[0];
  const float* W  = (const float*)d_in[1];
  const float* aw = (const float*)d_in[2];
  const float* ab = (const float*)d_in[3];
  const int*   ei = (const int*)d_in[4];

  float* out   = (float*)d_out;
  float* alpha = out + (size_t)N_NODES * N_HID;

  // workspace layout (4B units)
  unsigned short* Whb = (unsigned short*)d_ws;          // 6,400,000 ushort
  unsigned short* WbT = Whb + (size_t)N_NODES * N_HID;  // 16,384 ushort
  float* s1      = (float*)(WbT + 16384);               // 100,000
  float* s2      = s1 + N_NODES;                        // 100,000
  float* invh    = s2 + N_NODES;                        // 100,000
  int2*  binned  = (int2*)(invh + N_NODES);             // NBUCKET*BCAP records
  float* h_orig  = (float*)(binned + (size_t)NBUCKET * BCAP);  // 1,600,000
  int*   cursor  = (int*)(h_orig + N_EDGES);            // NBUCKET
  int*   tileCnt = cursor + NBUCKET;                    // NTILES*NBUCKET

  k_wprep<<<64, 256, 0, stream>>>(W, WbT, cursor);
  k_histT<<<NTILES, 256, 0, stream>>>(ei, tileCnt);
  k_gemm<<<(N_NODES + 63) / 64, 256, 0, stream>>>(x, WbT, aw, Whb, s1, s2);
  k_bin<<<NTILES, 256, 0, stream>>>(ei, s1, s2, ab, tileCnt, cursor, binned,
                                    h_orig);
  k_bucket<<<NBUCKET, BTHREADS, 0, stream>>>(cursor, binned, Whb, out, invh);
  k_alpha<<<(N_EDGES + 255) / 256, 256, 0, stream>>>(ei, h_orig, invh, alpha);
}

// Round 9
// 272.322 us; speedup vs baseline: 1.1485x; 1.1485x over previous
//
#include <hip/hip_runtime.h>

#define N_NODES 100000
#define N_FEAT  256
#define N_HID   64
#define N_EDGES 1600000
#define NEG_SLOPE 0.05f

#define NBUCKET 391   // ceil(N_NODES / 256); bucket b = nodes [b*256, b*256+256)
#define TILE    2048  // edges per tile
#define NTILES  ((N_EDGES + TILE - 1) / TILE)  // 782
#define HBCAP   2432  // per-HALF-bucket LDS record capacity (mean 2048, +8.5 sigma)
#define BTHREADS 1024 // k_bucket block size (16 waves; 2 blocks/CU co-resident)

typedef float  floatx4 __attribute__((ext_vector_type(4)));
typedef short  shortx8 __attribute__((ext_vector_type(8)));

__device__ __forceinline__ unsigned short f2bf(float f) {
  unsigned int u = __float_as_uint(f);
  u = u + 0x7fffu + ((u >> 16) & 1u);  // RNE
  return (unsigned short)(u >> 16);
}
__device__ __forceinline__ float bf_lo(unsigned int u) {
  return __uint_as_float(u << 16);
}
__device__ __forceinline__ float bf_hi(unsigned int u) {
  return __uint_as_float(u & 0xFFFF0000u);
}

// wave64 inclusive scan (no barriers)
__device__ __forceinline__ int wave_iscan(int v, int lane) {
#pragma unroll
  for (int d = 1; d < 64; d <<= 1) {
    int tv = __shfl_up(v, d);
    if (lane >= d) v += tv;
  }
  return v;
}

// ---------------------------------------------------------------------------
// K0: W prep — WbT[n][k] = bf16(W[k][n])
// ---------------------------------------------------------------------------
__global__ __launch_bounds__(256) void k_wprep(const float* __restrict__ W,
                                               unsigned short* __restrict__ WbT) {
  int n = blockIdx.x;
  int k = threadIdx.x;
  WbT[n * 256 + k] = f2bf(W[(size_t)k * N_HID + n]);
}

// ---------------------------------------------------------------------------
// K1: MFMA bf16 GEMM (wave = 16 rows x 64 cols; A streamed from global),
//     fused s1/s2; Wh stored bf16.
// ---------------------------------------------------------------------------
#define WSTRIDE 264
__global__ __launch_bounds__(256) void k_gemm(
    const float* __restrict__ x, const unsigned short* __restrict__ WbT,
    const float* __restrict__ aw, unsigned short* __restrict__ Whb,
    float* __restrict__ s1, float* __restrict__ s2) {
  __shared__ unsigned short wsm[64 * WSTRIDE];

  const int t = threadIdx.x;
  for (int idx = t; idx < 64 * 32; idx += 256) {
    int row = idx >> 5, c16 = idx & 31;
    *(uint4*)(wsm + row * WSTRIDE + c16 * 8) =
        *(const uint4*)(WbT + row * 256 + c16 * 8);
  }
  __syncthreads();

  const int w = t >> 6;
  const int lane = t & 63;
  const int q = lane >> 4;
  const int li = lane & 15;
  const int r0 = blockIdx.x * 64;
  const int grow = r0 + w * 16 + li;
  const bool vrow = grow < N_NODES;

  float4 araw[16];
  if (vrow) {
    const float4* xr = (const float4*)(x + (size_t)grow * N_FEAT);
#pragma unroll
    for (int c = 0; c < 8; ++c) {
      araw[2 * c]     = xr[c * 8 + q * 2];
      araw[2 * c + 1] = xr[c * 8 + q * 2 + 1];
    }
  } else {
#pragma unroll
    for (int i = 0; i < 16; ++i) araw[i] = make_float4(0.f, 0.f, 0.f, 0.f);
  }

  floatx4 acc[4];
#pragma unroll
  for (int g = 0; g < 4; ++g) acc[g] = (floatx4){0.f, 0.f, 0.f, 0.f};

#pragma unroll
  for (int c = 0; c < 8; ++c) {
    float4 v0 = araw[2 * c], v1 = araw[2 * c + 1];
    shortx8 a;
    a[0] = (short)f2bf(v0.x); a[1] = (short)f2bf(v0.y);
    a[2] = (short)f2bf(v0.z); a[3] = (short)f2bf(v0.w);
    a[4] = (short)f2bf(v1.x); a[5] = (short)f2bf(v1.y);
    a[6] = (short)f2bf(v1.z); a[7] = (short)f2bf(v1.w);
#pragma unroll
    for (int g = 0; g < 4; ++g) {
      shortx8 b = *(const shortx8*)(wsm + (g * 16 + li) * WSTRIDE + c * 32 + q * 8);
      acc[g] = __builtin_amdgcn_mfma_f32_16x16x32_bf16(a, b, acc[g], 0, 0, 0);
    }
  }

#pragma unroll
  for (int j = 0; j < 4; ++j) {
    int r = r0 + w * 16 + q * 4 + j;
    if (r < N_NODES) {
#pragma unroll
      for (int g = 0; g < 4; ++g)
        Whb[(size_t)r * N_HID + g * 16 + li] = f2bf(acc[g][j]);
    }
  }

#pragma unroll
  for (int j = 0; j < 4; ++j) {
    float p1 = 0.f, p2 = 0.f;
#pragma unroll
    for (int g = 0; g < 4; ++g) {
      p1 += acc[g][j] * aw[g * 16 + li];
      p2 += acc[g][j] * aw[64 + g * 16 + li];
    }
#pragma unroll
    for (int off = 1; off < 16; off <<= 1) {
      p1 += __shfl_xor(p1, off);
      p2 += __shfl_xor(p2, off);
    }
    int r = r0 + w * 16 + q * 4 + j;
    if (li == 0 && r < N_NODES) {
      s1[r] = p1;
      s2[r] = p2;
    }
  }
}

// ---------------------------------------------------------------------------
// K2: per-tile bucket histogram ONLY (LDS atomics, no global atomics).
// ---------------------------------------------------------------------------
__global__ __launch_bounds__(256) void k_histT(const int* __restrict__ ei,
                                               int* __restrict__ tileCnt) {
  __shared__ int hist[NBUCKET];
  const int t = threadIdx.x;
  const int e0 = blockIdx.x * TILE;
  const int ecnt = min(TILE, N_EDGES - e0);

  for (int i = t; i < NBUCKET; i += 256) hist[i] = 0;
  __syncthreads();

#pragma unroll
  for (int j = 0; j < 8; ++j) {
    int li = j * 256 + t;
    if (li < ecnt) atomicAdd(&hist[ei[e0 + li] >> 8], 1);
  }
  __syncthreads();

  for (int b = t; b < NBUCKET; b += 256)
    tileCnt[blockIdx.x * NBUCKET + b] = hist[b];
}

// ---------------------------------------------------------------------------
// K3a: per-bucket scan over tiles -> tileOff; bucket totals out.
//      1024 threads, single chunk (NTILES=782), wave-shuffle scan: 1 barrier.
// ---------------------------------------------------------------------------
__global__ __launch_bounds__(1024) void k_tilescan(
    const int* __restrict__ tileCnt, int* __restrict__ tileOff,
    int* __restrict__ buckTot) {
  __shared__ int wtot[16];
  const int b = blockIdx.x;
  const int t = threadIdx.x;
  const int lane = t & 63, wv = t >> 6;
  int v = (t < NTILES) ? tileCnt[t * NBUCKET + b] : 0;
  int p = wave_iscan(v, lane);
  if (lane == 63) wtot[wv] = p;
  __syncthreads();
  int off = 0;
  for (int w2 = 0; w2 < wv; ++w2) off += wtot[w2];
  if (t < NTILES) tileOff[t * NBUCKET + b] = off + p - v;
  if (t == 0) {
    int tot = 0;
#pragma unroll
    for (int w2 = 0; w2 < 16; ++w2) tot += wtot[w2];
    buckTot[b] = tot;
  }
}

// ---------------------------------------------------------------------------
// K3b: exclusive scan of 391 bucket totals -> buckStart (wave-shuffle)
// ---------------------------------------------------------------------------
__global__ __launch_bounds__(512) void k_bstart(const int* __restrict__ buckTot,
                                                int* __restrict__ buckStart) {
  __shared__ int wtot[8];
  const int t = threadIdx.x;
  const int lane = t & 63, wv = t >> 6;
  int v = (t < NBUCKET) ? buckTot[t] : 0;
  int p = wave_iscan(v, lane);
  if (lane == 63) wtot[wv] = p;
  __syncthreads();
  int off = 0;
  for (int w2 = 0; w2 < wv; ++w2) off += wtot[w2];
  if (t < NBUCKET) buckStart[t] = off + p - v;
  if (t == 0) buckStart[NBUCKET] = N_EDGES;
}

// ---------------------------------------------------------------------------
// K4: binned partition with DETERMINISTIC offsets — zero global atomics.
//     rec.x = dst | (src&255)<<17 ; rec.y = bits(h). h_orig[e] coalesced.
//     Bin-scan via wave shuffles (2 barriers instead of 16).
// ---------------------------------------------------------------------------
__global__ __launch_bounds__(256) void k_bin(
    const int* __restrict__ ei, const float* __restrict__ s1,
    const float* __restrict__ s2, const float* __restrict__ ab,
    const int* __restrict__ tileCnt, const int* __restrict__ tileOff,
    const int* __restrict__ buckStart, int2* __restrict__ binned,
    float* __restrict__ h_orig) {
  __shared__ int  hist[NBUCKET];
  __shared__ int  scanx[NBUCKET];
  __shared__ int  fillc[NBUCKET];
  __shared__ int  gbase[NBUCKET];
  __shared__ int  wtot[4];
  __shared__ int2 sorted[TILE];
  __shared__ int  tgt[TILE];

  const int t = threadIdx.x;
  const int tile = blockIdx.x;
  const int e0 = tile * TILE;
  const int ecnt = min(TILE, N_EDGES - e0);
  const int lane = t & 63, wv = t >> 6;

  for (int b = t; b < NBUCKET; b += 256) {
    hist[b] = tileCnt[tile * NBUCKET + b];
    gbase[b] = buckStart[b] + tileOff[tile * NBUCKET + b];
    fillc[b] = 0;
  }
  __syncthreads();

  // exclusive scan over hist (2 bins/thread), wave-shuffle
  int b0 = t * 2, b1 = t * 2 + 1;
  int v0 = (b0 < NBUCKET) ? hist[b0] : 0;
  int v1 = (b1 < NBUCKET) ? hist[b1] : 0;
  int pairsum = v0 + v1;
  int p = wave_iscan(pairsum, lane);
  if (lane == 63) wtot[wv] = p;
  __syncthreads();
  int off = 0;
  for (int w2 = 0; w2 < wv; ++w2) off += wtot[w2];
  int base = off + p - pairsum;
  if (b0 < NBUCKET) scanx[b0] = base;
  if (b1 < NBUCKET) scanx[b1] = base + v0;
  __syncthreads();

  float bias = ab[0];
#pragma unroll
  for (int j = 0; j < 8; ++j) {
    int li = j * 256 + t;
    if (li < ecnt) {
      int idx = e0 + li;
      int src = ei[idx];
      int dst = ei[N_EDGES + idx];
      float sc = s1[src] + s2[dst] + bias;
      float v = sc > 0.f ? sc : NEG_SLOPE * sc;
      float h = __expf(v);
      h_orig[idx] = h;
      int b = src >> 8;
      int slot = scanx[b] + atomicAdd(&fillc[b], 1);
      sorted[slot].x = dst | ((src & 255) << 17);
      sorted[slot].y = __float_as_int(h);
      tgt[slot] = gbase[b] + (slot - scanx[b]);
    }
  }
  __syncthreads();

  for (int i = t; i < ecnt; i += 256) binned[tgt[i]] = sorted[i];
}

// ---------------------------------------------------------------------------
// K5: TWO blocks per bucket (128 nodes each), 1024 threads (16 waves).
//     Each half-block scans the full bucket window, filters its half,
//     builds a local CSR (count -> shuffle-scan over 128 -> place), then
//     128 groups x 8 lanes aggregate (1 node/group) with deferred
//     normalization. LDS ~20.5KB -> 2 blocks (32 waves) co-reside per CU
//     with grid 782 (3.05/CU): full occupancy during the gather phase.
// ---------------------------------------------------------------------------
__global__ __launch_bounds__(BTHREADS, 8) void k_bucket(
    const int* __restrict__ buckStart, const int2* __restrict__ binned,
    const unsigned short* __restrict__ Whb, float* __restrict__ out,
    float* __restrict__ invh) {
  __shared__ int2  recs[HBCAP];
  __shared__ int   startp[128];
  __shared__ int   curs[128];
  __shared__ int   wtot[2];

  const int t = threadIdx.x;
  const int lane = t & 63;
  const int bb = blockIdx.x >> 1;     // bucket
  const int half = blockIdx.x & 1;    // 0: nodes 0..127, 1: nodes 128..255
  const int node0 = bb * 256 + half * 128;
  const int W0 = buckStart[bb];
  const int cnt = buckStart[bb + 1] - W0;

  if (t < 128) curs[t] = 0;
  __syncthreads();

  // pass 1: per-node count of this half (LDS atomics, L2-hot window)
  for (int i = t; i < cnt; i += BTHREADS) {
    int rx = binned[W0 + i].x;
    int loc = (rx >> 17) & 255;
    if ((loc >> 7) == half) atomicAdd(&curs[loc & 127], 1);
  }
  __syncthreads();

  // shuffle-scan of 128 counts -> exclusive startp (first 128 threads)
  int v = 0;
  if (t < 128) v = curs[t];
  int p = wave_iscan(v, lane);
  if (t < 128 && lane == 63) wtot[t >> 6] = p;
  __syncthreads();
  if (t < 128) {
    int off = (t >> 6) ? wtot[0] : 0;
    int mystart = off + p - v;
    startp[t] = mystart;
    curs[t] = mystart;
  }
  __syncthreads();

  // pass 2: place this half's records (normalization deferred)
  for (int i = t; i < cnt; i += BTHREADS) {
    int2 r = binned[W0 + i];
    int loc = (r.x >> 17) & 255;
    if ((loc >> 7) != half) continue;
    int slot = atomicAdd(&curs[loc & 127], 1);
    if (slot < HBCAP) {
      recs[slot].x = r.x & 0x1FFFF;
      recs[slot].y = r.y;
    }
  }
  __syncthreads();

  const int grp = t >> 3;   // 0..127 — one node per group
  const int li = t & 7;     // dims li*8..li*8+7
  int n2 = node0 + grp;
  if (n2 < N_NODES) {
    int beg = startp[grp];
    int endp = curs[grp];
    if (endp > HBCAP) endp = HBCAP;  // safety, statistically never
    float hs = 0.f;
    float acc[8] = {};
    int r = beg;
    // 4x unrolled: 4 LDS rec reads -> 4 independent 16B gathers in flight
    for (; r + 4 <= endp; r += 4) {
      int2 e0 = recs[r];
      int2 e1 = recs[r + 1];
      int2 e2 = recs[r + 2];
      int2 e3 = recs[r + 3];
      uint4 w0 = *(const uint4*)(Whb + (size_t)e0.x * N_HID + li * 8);
      uint4 w1 = *(const uint4*)(Whb + (size_t)e1.x * N_HID + li * 8);
      uint4 w2 = *(const uint4*)(Whb + (size_t)e2.x * N_HID + li * 8);
      uint4 w3 = *(const uint4*)(Whb + (size_t)e3.x * N_HID + li * 8);
      float a0 = __int_as_float(e0.y);
      float a1 = __int_as_float(e1.y);
      float a2 = __int_as_float(e2.y);
      float a3 = __int_as_float(e3.y);
      hs += (a0 + a1) + (a2 + a3);
      acc[0] += a0 * bf_lo(w0.x); acc[1] += a0 * bf_hi(w0.x);
      acc[2] += a0 * bf_lo(w0.y); acc[3] += a0 * bf_hi(w0.y);
      acc[4] += a0 * bf_lo(w0.z); acc[5] += a0 * bf_hi(w0.z);
      acc[6] += a0 * bf_lo(w0.w); acc[7] += a0 * bf_hi(w0.w);
      acc[0] += a1 * bf_lo(w1.x); acc[1] += a1 * bf_hi(w1.x);
      acc[2] += a1 * bf_lo(w1.y); acc[3] += a1 * bf_hi(w1.y);
      acc[4] += a1 * bf_lo(w1.z); acc[5] += a1 * bf_hi(w1.z);
      acc[6] += a1 * bf_lo(w1.w); acc[7] += a1 * bf_hi(w1.w);
      acc[0] += a2 * bf_lo(w2.x); acc[1] += a2 * bf_hi(w2.x);
      acc[2] += a2 * bf_lo(w2.y); acc[3] += a2 * bf_hi(w2.y);
      acc[4] += a2 * bf_lo(w2.z); acc[5] += a2 * bf_hi(w2.z);
      acc[6] += a2 * bf_lo(w2.w); acc[7] += a2 * bf_hi(w2.w);
      acc[0] += a3 * bf_lo(w3.x); acc[1] += a3 * bf_hi(w3.x);
      acc[2] += a3 * bf_lo(w3.y); acc[3] += a3 * bf_hi(w3.y);
      acc[4] += a3 * bf_lo(w3.z); acc[5] += a3 * bf_hi(w3.z);
      acc[6] += a3 * bf_lo(w3.w); acc[7] += a3 * bf_hi(w3.w);
    }
    for (; r < endp; ++r) {
      int2 rec = recs[r];
      float a = __int_as_float(rec.y);
      hs += a;
      uint4 wvv = *(const uint4*)(Whb + (size_t)rec.x * N_HID + li * 8);
      acc[0] += a * bf_lo(wvv.x); acc[1] += a * bf_hi(wvv.x);
      acc[2] += a * bf_lo(wvv.y); acc[3] += a * bf_hi(wvv.y);
      acc[4] += a * bf_lo(wvv.z); acc[5] += a * bf_hi(wvv.z);
      acc[6] += a * bf_lo(wvv.w); acc[7] += a * bf_hi(wvv.w);
    }
    float inv = (endp > beg) ? 1.f / hs : 0.f;
    if (li == 0) invh[n2] = inv;
#pragma unroll
    for (int k = 0; k < 8; ++k) acc[k] *= inv;
    float* op = out + (size_t)n2 * N_HID + li * 8;
    *(float4*)op = make_float4(acc[0], acc[1], acc[2], acc[3]);
    *(float4*)(op + 4) = make_float4(acc[4], acc[5], acc[6], acc[7]);
  }
}

// ---------------------------------------------------------------------------
// K6: alpha[e] = h_orig[e] * invh[src]
// ---------------------------------------------------------------------------
__global__ __launch_bounds__(256) void k_alpha(
    const int* __restrict__ ei, const float* __restrict__ h_orig,
    const float* __restrict__ invh, float* __restrict__ alpha) {
  int e = blockIdx.x * 256 + threadIdx.x;
  if (e >= N_EDGES) return;
  alpha[e] = h_orig[e] * invh[ei[e]];
}

extern "C" void kernel_launch(void* const* d_in, const int* in_sizes, int n_in,
                              void* d_out, int out_size, void* d_ws,
                              size_t ws_size, hipStream_t stream) {
  const float* x  = (const float*)d_in[0];
  const float* W  = (const float*)d_in[1];
  const float* aw = (const float*)d_in[2];
  const float* ab = (const float*)d_in[3];
  const int*   ei = (const int*)d_in[4];

  float* out   = (float*)d_out;
  float* alpha = out + (size_t)N_NODES * N_HID;

  // workspace layout (4B units)
  unsigned short* Whb = (unsigned short*)d_ws;          // 6,400,000 ushort
  unsigned short* WbT = Whb + (size_t)N_NODES * N_HID;  // 16,384 ushort
  float* s1      = (float*)(WbT + 16384);               // 100,000
  float* s2      = s1 + N_NODES;                        // 100,000
  float* invh    = s2 + N_NODES;                        // 100,000
  int2*  binned  = (int2*)(invh + N_NODES);             // 1,600,000 int2
  float* h_orig  = (float*)(binned + N_EDGES);          // 1,600,000
  int*   tileCnt = (int*)(h_orig + N_EDGES);            // NTILES*NBUCKET
  int*   tileOff = tileCnt + NTILES * NBUCKET;          // NTILES*NBUCKET
  int*   buckTot = tileOff + NTILES * NBUCKET;          // NBUCKET
  int*   buckStart = buckTot + NBUCKET;                 // NBUCKET+1

  k_wprep<<<64, 256, 0, stream>>>(W, WbT);
  k_histT<<<NTILES, 256, 0, stream>>>(ei, tileCnt);
  k_tilescan<<<NBUCKET, 1024, 0, stream>>>(tileCnt, tileOff, buckTot);
  k_bstart<<<1, 512, 0, stream>>>(buckTot, buckStart);

  k_gemm<<<(N_NODES + 63) / 64, 256, 0, stream>>>(x, WbT, aw, Whb, s1, s2);

  k_bin<<<NTILES, 256, 0, stream>>>(ei, s1, s2, ab, tileCnt, tileOff,
                                    buckStart, binned, h_orig);
  k_bucket<<<NBUCKET * 2, BTHREADS, 0, stream>>>(buckStart, binned, Whb, out,
                                                 invh);
  k_alpha<<<(N_EDGES + 255) / 256, 256, 0, stream>>>(ei, h_orig, invh, alpha);
}

// Round 10
// 262.358 us; speedup vs baseline: 1.1921x; 1.0380x over previous
//
#include <hip/hip_runtime.h>

#define N_NODES 100000
#define N_FEAT  256
#define N_HID   64
#define N_EDGES 1600000
#define NEG_SLOPE 0.05f

#define NBUCKET 391   // ceil(N_NODES / 256); bucket b = nodes [b*256, b*256+256)
#define TILE    2048  // edges per tile
#define NTILES  ((N_EDGES + TILE - 1) / TILE)  // 782
#define BCAP    4704  // per-bucket LDS record capacity (mean 4092, +9.5 sigma)
#define BTHREADS 1024 // k_bucket block size (16 waves; 2 blocks/CU co-resident)
#define RSTASH  5     // ceil(BCAP / BTHREADS) register-stash depth

typedef float  floatx4 __attribute__((ext_vector_type(4)));
typedef short  shortx8 __attribute__((ext_vector_type(8)));

__device__ __forceinline__ unsigned short f2bf(float f) {
  unsigned int u = __float_as_uint(f);
  u = u + 0x7fffu + ((u >> 16) & 1u);  // RNE
  return (unsigned short)(u >> 16);
}
__device__ __forceinline__ float bf_lo(unsigned int u) {
  return __uint_as_float(u << 16);
}
__device__ __forceinline__ float bf_hi(unsigned int u) {
  return __uint_as_float(u & 0xFFFF0000u);
}

// wave64 inclusive scan (no barriers)
__device__ __forceinline__ int wave_iscan(int v, int lane) {
#pragma unroll
  for (int d = 1; d < 64; d <<= 1) {
    int tv = __shfl_up(v, d);
    if (lane >= d) v += tv;
  }
  return v;
}

// ---------------------------------------------------------------------------
// K2: per-tile bucket histogram (LDS atomics). Blocks 0..63 additionally
//     transpose W -> WbT bf16 (absorbs the old k_wprep launch).
// ---------------------------------------------------------------------------
__global__ __launch_bounds__(256) void k_histT(const float* __restrict__ W,
                                               unsigned short* __restrict__ WbT,
                                               const int* __restrict__ ei,
                                               int* __restrict__ tileCnt) {
  __shared__ int hist[NBUCKET];
  const int t = threadIdx.x;
  const int e0 = blockIdx.x * TILE;
  const int ecnt = min(TILE, N_EDGES - e0);

  if (blockIdx.x < 64)
    WbT[blockIdx.x * 256 + t] = f2bf(W[(size_t)t * N_HID + blockIdx.x]);

  for (int i = t; i < NBUCKET; i += 256) hist[i] = 0;
  __syncthreads();

#pragma unroll
  for (int j = 0; j < 8; ++j) {
    int li = j * 256 + t;
    if (li < ecnt) atomicAdd(&hist[ei[e0 + li] >> 8], 1);
  }
  __syncthreads();

  for (int b = t; b < NBUCKET; b += 256)
    tileCnt[blockIdx.x * NBUCKET + b] = hist[b];
}

// ---------------------------------------------------------------------------
// K1: MFMA bf16 GEMM (wave = 16 rows x 64 cols; A streamed from global),
//     fused s1/s2; Wh stored bf16.
// ---------------------------------------------------------------------------
#define WSTRIDE 264
__global__ __launch_bounds__(256) void k_gemm(
    const float* __restrict__ x, const unsigned short* __restrict__ WbT,
    const float* __restrict__ aw, unsigned short* __restrict__ Whb,
    float* __restrict__ s1, float* __restrict__ s2) {
  __shared__ unsigned short wsm[64 * WSTRIDE];

  const int t = threadIdx.x;
  for (int idx = t; idx < 64 * 32; idx += 256) {
    int row = idx >> 5, c16 = idx & 31;
    *(uint4*)(wsm + row * WSTRIDE + c16 * 8) =
        *(const uint4*)(WbT + row * 256 + c16 * 8);
  }
  __syncthreads();

  const int w = t >> 6;
  const int lane = t & 63;
  const int q = lane >> 4;
  const int li = lane & 15;
  const int r0 = blockIdx.x * 64;
  const int grow = r0 + w * 16 + li;
  const bool vrow = grow < N_NODES;

  float4 araw[16];
  if (vrow) {
    const float4* xr = (const float4*)(x + (size_t)grow * N_FEAT);
#pragma unroll
    for (int c = 0; c < 8; ++c) {
      araw[2 * c]     = xr[c * 8 + q * 2];
      araw[2 * c + 1] = xr[c * 8 + q * 2 + 1];
    }
  } else {
#pragma unroll
    for (int i = 0; i < 16; ++i) araw[i] = make_float4(0.f, 0.f, 0.f, 0.f);
  }

  floatx4 acc[4];
#pragma unroll
  for (int g = 0; g < 4; ++g) acc[g] = (floatx4){0.f, 0.f, 0.f, 0.f};

#pragma unroll
  for (int c = 0; c < 8; ++c) {
    float4 v0 = araw[2 * c], v1 = araw[2 * c + 1];
    shortx8 a;
    a[0] = (short)f2bf(v0.x); a[1] = (short)f2bf(v0.y);
    a[2] = (short)f2bf(v0.z); a[3] = (short)f2bf(v0.w);
    a[4] = (short)f2bf(v1.x); a[5] = (short)f2bf(v1.y);
    a[6] = (short)f2bf(v1.z); a[7] = (short)f2bf(v1.w);
#pragma unroll
    for (int g = 0; g < 4; ++g) {
      shortx8 b = *(const shortx8*)(wsm + (g * 16 + li) * WSTRIDE + c * 32 + q * 8);
      acc[g] = __builtin_amdgcn_mfma_f32_16x16x32_bf16(a, b, acc[g], 0, 0, 0);
    }
  }

#pragma unroll
  for (int j = 0; j < 4; ++j) {
    int r = r0 + w * 16 + q * 4 + j;
    if (r < N_NODES) {
#pragma unroll
      for (int g = 0; g < 4; ++g)
        Whb[(size_t)r * N_HID + g * 16 + li] = f2bf(acc[g][j]);
    }
  }

#pragma unroll
  for (int j = 0; j < 4; ++j) {
    float p1 = 0.f, p2 = 0.f;
#pragma unroll
    for (int g = 0; g < 4; ++g) {
      p1 += acc[g][j] * aw[g * 16 + li];
      p2 += acc[g][j] * aw[64 + g * 16 + li];
    }
#pragma unroll
    for (int off = 1; off < 16; off <<= 1) {
      p1 += __shfl_xor(p1, off);
      p2 += __shfl_xor(p2, off);
    }
    int r = r0 + w * 16 + q * 4 + j;
    if (li == 0 && r < N_NODES) {
      s1[r] = p1;
      s2[r] = p2;
    }
  }
}

// ---------------------------------------------------------------------------
// K3a: per-bucket scan over tiles -> tileOff; bucket totals out.
//      1024 threads, single chunk (NTILES=782), wave-shuffle scan: 1 barrier.
// ---------------------------------------------------------------------------
__global__ __launch_bounds__(1024) void k_tilescan(
    const int* __restrict__ tileCnt, int* __restrict__ tileOff,
    int* __restrict__ buckTot) {
  __shared__ int wtot[16];
  const int b = blockIdx.x;
  const int t = threadIdx.x;
  const int lane = t & 63, wv = t >> 6;
  int v = (t < NTILES) ? tileCnt[t * NBUCKET + b] : 0;
  int p = wave_iscan(v, lane);
  if (lane == 63) wtot[wv] = p;
  __syncthreads();
  int off = 0;
  for (int w2 = 0; w2 < wv; ++w2) off += wtot[w2];
  if (t < NTILES) tileOff[t * NBUCKET + b] = off + p - v;
  if (t == 0) {
    int tot = 0;
#pragma unroll
    for (int w2 = 0; w2 < 16; ++w2) tot += wtot[w2];
    buckTot[b] = tot;
  }
}

// ---------------------------------------------------------------------------
// K3b: exclusive scan of 391 bucket totals -> buckStart (wave-shuffle)
// ---------------------------------------------------------------------------
__global__ __launch_bounds__(512) void k_bstart(const int* __restrict__ buckTot,
                                                int* __restrict__ buckStart) {
  __shared__ int wtot[8];
  const int t = threadIdx.x;
  const int lane = t & 63, wv = t >> 6;
  int v = (t < NBUCKET) ? buckTot[t] : 0;
  int p = wave_iscan(v, lane);
  if (lane == 63) wtot[wv] = p;
  __syncthreads();
  int off = 0;
  for (int w2 = 0; w2 < wv; ++w2) off += wtot[w2];
  if (t < NBUCKET) buckStart[t] = off + p - v;
  if (t == 0) buckStart[NBUCKET] = N_EDGES;
}

// ---------------------------------------------------------------------------
// K4: binned partition with DETERMINISTIC offsets — zero global atomics.
//     rec.x = dst | (src&255)<<17 ; rec.y = bits(h). h_orig[e] coalesced.
//     Bin-scan via wave shuffles (2 barriers instead of 16).
// ---------------------------------------------------------------------------
__global__ __launch_bounds__(256) void k_bin(
    const int* __restrict__ ei, const float* __restrict__ s1,
    const float* __restrict__ s2, const float* __restrict__ ab,
    const int* __restrict__ tileCnt, const int* __restrict__ tileOff,
    const int* __restrict__ buckStart, int2* __restrict__ binned,
    float* __restrict__ h_orig) {
  __shared__ int  hist[NBUCKET];
  __shared__ int  scanx[NBUCKET];
  __shared__ int  fillc[NBUCKET];
  __shared__ int  gbase[NBUCKET];
  __shared__ int  wtot[4];
  __shared__ int2 sorted[TILE];
  __shared__ int  tgt[TILE];

  const int t = threadIdx.x;
  const int tile = blockIdx.x;
  const int e0 = tile * TILE;
  const int ecnt = min(TILE, N_EDGES - e0);
  const int lane = t & 63, wv = t >> 6;

  for (int b = t; b < NBUCKET; b += 256) {
    hist[b] = tileCnt[tile * NBUCKET + b];
    gbase[b] = buckStart[b] + tileOff[tile * NBUCKET + b];
    fillc[b] = 0;
  }
  __syncthreads();

  // exclusive scan over hist (2 bins/thread), wave-shuffle
  int b0 = t * 2, b1 = t * 2 + 1;
  int v0 = (b0 < NBUCKET) ? hist[b0] : 0;
  int v1 = (b1 < NBUCKET) ? hist[b1] : 0;
  int pairsum = v0 + v1;
  int p = wave_iscan(pairsum, lane);
  if (lane == 63) wtot[wv] = p;
  __syncthreads();
  int off = 0;
  for (int w2 = 0; w2 < wv; ++w2) off += wtot[w2];
  int base = off + p - pairsum;
  if (b0 < NBUCKET) scanx[b0] = base;
  if (b1 < NBUCKET) scanx[b1] = base + v0;
  __syncthreads();

  float bias = ab[0];
#pragma unroll
  for (int j = 0; j < 8; ++j) {
    int li = j * 256 + t;
    if (li < ecnt) {
      int idx = e0 + li;
      int src = ei[idx];
      int dst = ei[N_EDGES + idx];
      float sc = s1[src] + s2[dst] + bias;
      float v = sc > 0.f ? sc : NEG_SLOPE * sc;
      float h = __expf(v);
      h_orig[idx] = h;
      int b = src >> 8;
      int slot = scanx[b] + atomicAdd(&fillc[b], 1);
      sorted[slot].x = dst | ((src & 255) << 17);
      sorted[slot].y = __float_as_int(h);
      tgt[slot] = gbase[b] + (slot - scanx[b]);
    }
  }
  __syncthreads();

  for (int i = t; i < ecnt; i += 256) binned[tgt[i]] = sorted[i];
}

// ---------------------------------------------------------------------------
// K5: one block per bucket (256 nodes), 1024 threads (16 waves).
//     Pass 1 loads each record ONCE into registers (<=5/thread, statically
//     indexed) and counts; pass 2 replays from registers — the second
//     12.8MB binned read is eliminated. Shuffle-scan startp, then 128
//     groups x 8 lanes aggregate with deferred normalization.
//     __launch_bounds__(1024,8) keeps VGPR <= 64 (2 blocks = 32 waves/CU).
// ---------------------------------------------------------------------------
__global__ __launch_bounds__(BTHREADS, 8) void k_bucket(
    const int* __restrict__ buckStart, const int2* __restrict__ binned,
    const unsigned short* __restrict__ Whb, float* __restrict__ out,
    float* __restrict__ invh) {
  __shared__ int2  recs[BCAP];
  __shared__ int   startp[256];
  __shared__ int   curs[256];
  __shared__ int   wtot[4];

  const int t = threadIdx.x;
  const int lane = t & 63, wvx = t >> 6;
  const int b = blockIdx.x;
  const int node0 = b * 256;
  const int W0 = buckStart[b];
  const int W1 = buckStart[b + 1];
  const int cnt = min(W1 - W0, RSTASH * BTHREADS);

  if (t < 256) curs[t] = 0;
  __syncthreads();

  // pass 1: load records once (register stash) + per-node count
  int2 myrec[RSTASH];
#pragma unroll
  for (int c = 0; c < RSTASH; ++c) {
    int i = c * BTHREADS + t;
    if (i < cnt) {
      int2 r = binned[W0 + i];
      myrec[c] = r;
      atomicAdd(&curs[(r.x >> 17) & 255], 1);
    }
  }
  __syncthreads();

  // shuffle-scan of counts -> exclusive startp (first 256 threads)
  int v = 0;
  if (t < 256) v = curs[t];
  int p = wave_iscan(v, lane);
  if (t < 256 && lane == 63) wtot[wvx] = p;
  __syncthreads();
  if (t < 256) {
    int off = 0;
    for (int w2 = 0; w2 < wvx; ++w2) off += wtot[w2];
    int mystart = off + p - v;
    startp[t] = mystart;
    curs[t] = mystart;
  }
  __syncthreads();

  // pass 2: place records from registers (no global reload)
#pragma unroll
  for (int c = 0; c < RSTASH; ++c) {
    int i = c * BTHREADS + t;
    if (i < cnt) {
      int2 r = myrec[c];
      int loc = (r.x >> 17) & 255;
      int slot = atomicAdd(&curs[loc], 1);
      if (slot < BCAP) {
        recs[slot].x = r.x & 0x1FFFF;
        recs[slot].y = r.y;
      }
    }
  }
  __syncthreads();

  const int wv = t >> 6, lane2 = t & 63;
  const int grp = (wv << 3) | (lane2 >> 3);  // 0..127
  const int li = lane2 & 7;                  // dims li*8..li*8+7
  for (int j = grp; j < 256; j += 128) {
    int n2 = node0 + j;
    if (n2 >= N_NODES) break;
    int beg = startp[j];
    int endp = curs[j];
    if (endp > BCAP) endp = BCAP;  // safety, statistically never
    float hs = 0.f;
    float acc[8] = {};
    int r = beg;
    // 4x unrolled: 4 LDS rec reads -> 4 independent 16B gathers in flight
    for (; r + 4 <= endp; r += 4) {
      int2 e0 = recs[r];
      int2 e1 = recs[r + 1];
      int2 e2 = recs[r + 2];
      int2 e3 = recs[r + 3];
      uint4 w0 = *(const uint4*)(Whb + (size_t)e0.x * N_HID + li * 8);
      uint4 w1 = *(const uint4*)(Whb + (size_t)e1.x * N_HID + li * 8);
      uint4 w2 = *(const uint4*)(Whb + (size_t)e2.x * N_HID + li * 8);
      uint4 w3 = *(const uint4*)(Whb + (size_t)e3.x * N_HID + li * 8);
      float a0 = __int_as_float(e0.y);
      float a1 = __int_as_float(e1.y);
      float a2 = __int_as_float(e2.y);
      float a3 = __int_as_float(e3.y);
      hs += (a0 + a1) + (a2 + a3);
      acc[0] += a0 * bf_lo(w0.x); acc[1] += a0 * bf_hi(w0.x);
      acc[2] += a0 * bf_lo(w0.y); acc[3] += a0 * bf_hi(w0.y);
      acc[4] += a0 * bf_lo(w0.z); acc[5] += a0 * bf_hi(w0.z);
      acc[6] += a0 * bf_lo(w0.w); acc[7] += a0 * bf_hi(w0.w);
      acc[0] += a1 * bf_lo(w1.x); acc[1] += a1 * bf_hi(w1.x);
      acc[2] += a1 * bf_lo(w1.y); acc[3] += a1 * bf_hi(w1.y);
      acc[4] += a1 * bf_lo(w1.z); acc[5] += a1 * bf_hi(w1.z);
      acc[6] += a1 * bf_lo(w1.w); acc[7] += a1 * bf_hi(w1.w);
      acc[0] += a2 * bf_lo(w2.x); acc[1] += a2 * bf_hi(w2.x);
      acc[2] += a2 * bf_lo(w2.y); acc[3] += a2 * bf_hi(w2.y);
      acc[4] += a2 * bf_lo(w2.z); acc[5] += a2 * bf_hi(w2.z);
      acc[6] += a2 * bf_lo(w2.w); acc[7] += a2 * bf_hi(w2.w);
      acc[0] += a3 * bf_lo(w3.x); acc[1] += a3 * bf_hi(w3.x);
      acc[2] += a3 * bf_lo(w3.y); acc[3] += a3 * bf_hi(w3.y);
      acc[4] += a3 * bf_lo(w3.z); acc[5] += a3 * bf_hi(w3.z);
      acc[6] += a3 * bf_lo(w3.w); acc[7] += a3 * bf_hi(w3.w);
    }
    for (; r < endp; ++r) {
      int2 rec = recs[r];
      float a = __int_as_float(rec.y);
      hs += a;
      uint4 wvv = *(const uint4*)(Whb + (size_t)rec.x * N_HID + li * 8);
      acc[0] += a * bf_lo(wvv.x); acc[1] += a * bf_hi(wvv.x);
      acc[2] += a * bf_lo(wvv.y); acc[3] += a * bf_hi(wvv.y);
      acc[4] += a * bf_lo(wvv.z); acc[5] += a * bf_hi(wvv.z);
      acc[6] += a * bf_lo(wvv.w); acc[7] += a * bf_hi(wvv.w);
    }
    float inv = (endp > beg) ? 1.f / hs : 0.f;
    if (li == 0) invh[n2] = inv;
#pragma unroll
    for (int k = 0; k < 8; ++k) acc[k] *= inv;
    float* op = out + (size_t)n2 * N_HID + li * 8;
    *(float4*)op = make_float4(acc[0], acc[1], acc[2], acc[3]);
    *(float4*)(op + 4) = make_float4(acc[4], acc[5], acc[6], acc[7]);
  }
}

// ---------------------------------------------------------------------------
// K6: alpha[e] = h_orig[e] * invh[src]
// ---------------------------------------------------------------------------
__global__ __launch_bounds__(256) void k_alpha(
    const int* __restrict__ ei, const float* __restrict__ h_orig,
    const float* __restrict__ invh, float* __restrict__ alpha) {
  int e = blockIdx.x * 256 + threadIdx.x;
  if (e >= N_EDGES) return;
  alpha[e] = h_orig[e] * invh[ei[e]];
}

extern "C" void kernel_launch(void* const* d_in, const int* in_sizes, int n_in,
                              void* d_out, int out_size, void* d_ws,
                              size_t ws_size, hipStream_t stream) {
  const float* x  = (const float*)d_in[0];
  const float* W  = (const float*)d_in[1];
  const float* aw = (const float*)d_in[2];
  const float* ab = (const float*)d_in[3];
  const int*   ei = (const int*)d_in[4];

  float* out   = (float*)d_out;
  float* alpha = out + (size_t)N_NODES * N_HID;

  // workspace layout (4B units)
  unsigned short* Whb = (unsigned short*)d_ws;          // 6,400,000 ushort
  unsigned short* WbT = Whb + (size_t)N_NODES * N_HID;  // 16,384 ushort
  float* s1      = (float*)(WbT + 16384);               // 100,000
  float* s2      = s1 + N_NODES;                        // 100,000
  float* invh    = s2 + N_NODES;                        // 100,000
  int2*  binned  = (int2*)(invh + N_NODES);             // 1,600,000 int2
  float* h_orig  = (float*)(binned + N_EDGES);          // 1,600,000
  int*   tileCnt = (int*)(h_orig + N_EDGES);            // NTILES*NBUCKET
  int*   tileOff = tileCnt + NTILES * NBUCKET;          // NTILES*NBUCKET
  int*   buckTot = tileOff + NTILES * NBUCKET;          // NBUCKET
  int*   buckStart = buckTot + NBUCKET;                 // NBUCKET+1

  k_histT<<<NTILES, 256, 0, stream>>>(W, WbT, ei, tileCnt);
  k_tilescan<<<NBUCKET, 1024, 0, stream>>>(tileCnt, tileOff, buckTot);
  k_bstart<<<1, 512, 0, stream>>>(buckTot, buckStart);

  k_gemm<<<(N_NODES + 63) / 64, 256, 0, stream>>>(x, WbT, aw, Whb, s1, s2);

  k_bin<<<NTILES, 256, 0, stream>>>(ei, s1, s2, ab, tileCnt, tileOff,
                                    buckStart, binned, h_orig);
  k_bucket<<<NBUCKET, BTHREADS, 0, stream>>>(buckStart, binned, Whb, out, invh);
  k_alpha<<<(N_EDGES + 255) / 256, 256, 0, stream>>>(ei, h_orig, invh, alpha);
}